// Round 1
// baseline (84.094 us; speedup 1.0000x reference)
//
#include <hip/hip_runtime.h>

// ---------------------------------------------------------------------------
// tNet: the einsum chain is linear in x. Precompute W_eff (1024x1024), then
//   h = relu(X @ W_eff^T + bias1);  out = h @ fc2_w^T + fc2_b
// Index derivation (verified against reference einsums):
//   t5[z,d,r,t] = sum_{a,b,c,e,p,q,s} x[z,a,b,c] u1[a,d,e] b2[e,p,q]
//                                     u2[b,r,p] b1c[q,s] u3[c,t,s]
// Output flat index o = d*128 + r*16 + t, input flat index i = a*128+b*16+c.
// Staged build: C2[e,p,s] = sum_q b2[e,p,q] b1c[q,s]
//               T1[a,d,p,s] = sum_e u1[a,d,e] C2[e,p,s]
//               T2[a,d,b,r,s] = sum_p T1[a,d,p,s] u2[b,r,p]
//               W[o,i] = sum_s T2[a,d,b,r,s] u3[c,t,s]
// ---------------------------------------------------------------------------

__global__ __launch_bounds__(256) void k_build_c2(const float* __restrict__ b2,
                                                  const float* __restrict__ b1c,
                                                  float* __restrict__ C2) {
    int idx = blockIdx.x * 256 + threadIdx.x;          // 4096 = [e][p][s]
    int e = idx >> 8, p = (idx >> 4) & 15, s = idx & 15;
    float acc = 0.f;
#pragma unroll
    for (int q = 0; q < 16; ++q) acc += b2[e * 256 + p * 16 + q] * b1c[q * 16 + s];
    C2[idx] = acc;
}

__global__ __launch_bounds__(256) void k_build_t1(const float* __restrict__ u1,
                                                  const float* __restrict__ C2,
                                                  float* __restrict__ T1) {
    int idx = blockIdx.x * 256 + threadIdx.x;          // 16384 = [a*8+d][p][s]
    int s = idx & 15, p = (idx >> 4) & 15, ad = idx >> 8;
    float acc = 0.f;
#pragma unroll
    for (int e = 0; e < 16; ++e) acc += u1[ad * 16 + e] * C2[e * 256 + p * 16 + s];
    T1[idx] = acc;
}

__global__ __launch_bounds__(256) void k_build_t2(const float* __restrict__ T1,
                                                  const float* __restrict__ u2,
                                                  float* __restrict__ T2) {
    int idx = blockIdx.x * 256 + threadIdx.x;          // 65536 = [ad][b][r][s]
    int s = idx & 15, r = (idx >> 4) & 7, b = (idx >> 7) & 7, ad = idx >> 10;
    float acc = 0.f;
#pragma unroll
    for (int p = 0; p < 16; ++p)
        acc += T1[(ad * 16 + p) * 16 + s] * u2[(b * 8 + r) * 16 + p];
    T2[idx] = acc;
}

__global__ __launch_bounds__(256) void k_build_w(const float* __restrict__ T2,
                                                 const float* __restrict__ u3,
                                                 float* __restrict__ Wm) {
    int flat = blockIdx.x * 256 + threadIdx.x;         // 1,048,576 = [o][i]
    int i = flat & 1023, o = flat >> 10;
    int c = i & 15, b = (i >> 4) & 7, a = i >> 7;
    int t = o & 15, r = (o >> 4) & 7, d = o >> 7;
    int ad = a * 8 + d;
    const float* t2p = &T2[((ad * 8 + b) * 8 + r) * 16];
    const float* u3p = &u3[c * 256 + t * 16];
    float acc = 0.f;
#pragma unroll
    for (int s = 0; s < 16; ++s) acc += t2p[s] * u3p[s];
    Wm[flat] = acc;
}

// ---------------------------------------------------------------------------
// Main GEMM: H[z][o] = relu( sum_i X[z][i] * W[o][i] + bias[o] )
// 64x64 tile, BK=32, 256 threads (16x16), 4x4 microtile.
// LDS stored transposed: As[k][m], Bs[k][n]; stride 68 keeps float4 reads
// 16B-aligned (68*4=272=17*16) and conflict-light.
// ---------------------------------------------------------------------------
#define BM 64
#define BN 64
#define BKK 32
#define LSTRIDE 68

__global__ __launch_bounds__(256) void k_gemm_bias_relu(
    const float* __restrict__ X, const float* __restrict__ Wm,
    const float* __restrict__ bias, float* __restrict__ H) {
    __shared__ float As[BKK][LSTRIDE];
    __shared__ float Bs[BKK][LSTRIDE];
    const int tid = threadIdx.x;
    const int tx = tid & 15;    // o direction
    const int ty = tid >> 4;    // z direction
    const int z0 = blockIdx.y * BM;
    const int o0 = blockIdx.x * BN;
    const int sr = tid >> 3;          // 0..31 staging row
    const int sc = (tid & 7) * 4;     // 0..28 staging k-col (float4)

    float acc[4][4] = {};

    for (int k0 = 0; k0 < 1024; k0 += BKK) {
#pragma unroll
        for (int p = 0; p < 2; ++p) {
            const int row = sr + 32 * p;
            float4 va = *(const float4*)(&X[(z0 + row) * 1024 + k0 + sc]);
            As[sc + 0][row] = va.x;
            As[sc + 1][row] = va.y;
            As[sc + 2][row] = va.z;
            As[sc + 3][row] = va.w;
            float4 vb = *(const float4*)(&Wm[(o0 + row) * 1024 + k0 + sc]);
            Bs[sc + 0][row] = vb.x;
            Bs[sc + 1][row] = vb.y;
            Bs[sc + 2][row] = vb.z;
            Bs[sc + 3][row] = vb.w;
        }
        __syncthreads();
#pragma unroll
        for (int k = 0; k < BKK; ++k) {
            float4 a4 = *(const float4*)(&As[k][ty * 4]);
            float4 b4 = *(const float4*)(&Bs[k][tx * 4]);
            float av[4] = {a4.x, a4.y, a4.z, a4.w};
            float bv[4] = {b4.x, b4.y, b4.z, b4.w};
#pragma unroll
            for (int i = 0; i < 4; ++i)
#pragma unroll
                for (int j = 0; j < 4; ++j) acc[i][j] += av[i] * bv[j];
        }
        __syncthreads();
    }

#pragma unroll
    for (int i = 0; i < 4; ++i) {
        const int z = z0 + ty * 4 + i;
        const int o = o0 + tx * 4;
        float4 r;
        r.x = fmaxf(acc[i][0] + bias[o + 0], 0.f);
        r.y = fmaxf(acc[i][1] + bias[o + 1], 0.f);
        r.z = fmaxf(acc[i][2] + bias[o + 2], 0.f);
        r.w = fmaxf(acc[i][3] + bias[o + 3], 0.f);
        *(float4*)(&H[z * 1024 + o]) = r;
    }
}

// ---------------------------------------------------------------------------
// fc2: out[z][j] = sum_o H[z][o] * W2[j][o] + b2[j], j < 10.
// One wave per z-row; H row cached in 16 regs/lane.
// ---------------------------------------------------------------------------
__global__ __launch_bounds__(256) void k_fc2(const float* __restrict__ H,
                                             const float* __restrict__ W2,
                                             const float* __restrict__ B2v,
                                             float* __restrict__ out) {
    const int tid = threadIdx.x;
    const int wave = tid >> 6;
    const int lane = tid & 63;
    const int z = blockIdx.x * 4 + wave;
    float h[16];
#pragma unroll
    for (int i = 0; i < 16; ++i) h[i] = H[z * 1024 + lane + 64 * i];
#pragma unroll
    for (int j = 0; j < 10; ++j) {
        float s = 0.f;
#pragma unroll
        for (int i = 0; i < 16; ++i) s += h[i] * W2[j * 1024 + lane + 64 * i];
#pragma unroll
        for (int off = 32; off > 0; off >>= 1) s += __shfl_down(s, off);
        if (lane == 0) out[z * 10 + j] = s + B2v[j];
    }
}

extern "C" void kernel_launch(void* const* d_in, const int* in_sizes, int n_in,
                              void* d_out, int out_size, void* d_ws, size_t ws_size,
                              hipStream_t stream) {
    const float* x     = (const float*)d_in[0];   // (1024,1024)
    const float* u1    = (const float*)d_in[1];   // (8,8,16)
    const float* u2    = (const float*)d_in[2];   // (8,8,16)
    const float* u3    = (const float*)d_in[3];   // (16,16,16)
    const float* b2    = (const float*)d_in[4];   // (16,16,16)
    const float* b1c   = (const float*)d_in[5];   // (16,16)
    const float* bias1 = (const float*)d_in[6];   // (8,8,16) -> flat 1024
    const float* fc2w  = (const float*)d_in[7];   // (10,1024)
    const float* fc2b  = (const float*)d_in[8];   // (10,)
    float* out = (float*)d_out;

    float* ws = (float*)d_ws;
    float* C2 = ws;                 // 4096
    float* T1 = C2 + 4096;          // 16384
    float* T2 = T1 + 16384;         // 65536
    float* Wm = T2 + 65536;         // 1048576
    float* H  = Wm + 1048576;       // 1048576  (total ~8.7 MB)

    k_build_c2<<<16, 256, 0, stream>>>(b2, b1c, C2);
    k_build_t1<<<64, 256, 0, stream>>>(u1, C2, T1);
    k_build_t2<<<256, 256, 0, stream>>>(T1, u2, T2);
    k_build_w<<<4096, 256, 0, stream>>>(T2, u3, Wm);
    k_gemm_bias_relu<<<dim3(16, 16), 256, 0, stream>>>(x, Wm, bias1, H);
    k_fc2<<<256, 256, 0, stream>>>(H, fc2w, fc2b, out);
}

// Round 2
// 40.911 us; speedup vs baseline: 2.0556x; 2.0556x over previous
//
#include <hip/hip_runtime.h>

// ---------------------------------------------------------------------------
// tNet: einsum chain is linear in x. Build W_eff (1024x1024, bf16) in ONE
// fused kernel, then H = relu(X @ W^T + bias1) via bf16 MFMA, then fc2.
//   t5[z,d,r,t] = sum_{a,b,c,e,p,q,s} x[z,a,b,c] u1[a,d,e] b2[e,p,q]
//                                     u2[b,r,p] b1c[q,s] u3[c,t,s]
//   o = d*128+r*16+t ; i = a*128+b*16+c
// Staged: C2[e,p,s]=sum_q b2*b1c ; T1[ad,p,s]=sum_e u1*C2 ;
//         T2[ad,b,r,s]=sum_p T1*u2 ; W[o,i]=sum_s T2*u3
// ---------------------------------------------------------------------------

using s16x8 = __attribute__((ext_vector_type(8))) short;   // 8 bf16
using f32x4 = __attribute__((ext_vector_type(4))) float;

__device__ inline short f2bf(float f) {
    unsigned u = __builtin_bit_cast(unsigned, f);
    u += 0x7fffu + ((u >> 16) & 1u);          // round-to-nearest-even
    return (short)(u >> 16);
}

// One block per ad (= a*8+d), 64 blocks x 256 threads.
__global__ __launch_bounds__(256) void k_build_w(
    const float* __restrict__ u1, const float* __restrict__ u2,
    const float* __restrict__ u3, const float* __restrict__ b2,
    const float* __restrict__ b1c, short* __restrict__ Wb) {
    __shared__ float b1s[256];
    __shared__ float C2f[4096];
    __shared__ float T1s[256];
    __shared__ float T2s[1024];
    const int tid = threadIdx.x;
    const int ad = blockIdx.x;                 // a = ad>>3, d = ad&7
    b1s[tid] = b1c[tid];
    __syncthreads();
    // C2[e,p,s]
    for (int j = 0; j < 16; ++j) {
        int idx = tid + 256 * j;
        int e = idx >> 8, p = (idx >> 4) & 15, s = idx & 15;
        float acc = 0.f;
#pragma unroll
        for (int q = 0; q < 16; ++q)
            acc += b2[e * 256 + p * 16 + q] * b1s[q * 16 + s];
        C2f[idx] = acc;
    }
    __syncthreads();
    // T1[p,s] for this ad
    {
        float acc = 0.f;
#pragma unroll
        for (int e = 0; e < 16; ++e)
            acc += u1[ad * 16 + e] * C2f[e * 256 + tid];
        T1s[tid] = acc;
    }
    __syncthreads();
    // T2[b,r,s]
    for (int j = 0; j < 4; ++j) {
        int idx = tid + 256 * j;
        int s = idx & 15, r = (idx >> 4) & 7, b = idx >> 7;
        float acc = 0.f;
#pragma unroll
        for (int p = 0; p < 16; ++p)
            acc += T1s[p * 16 + s] * u2[(b * 8 + r) * 16 + p];
        T2s[idx] = acc;
    }
    __syncthreads();
    // W rows o = d*128+r*16+t, cols i = a*128 + (bc)
    const int a = ad >> 3, d = ad & 7;
    const int rt = tid >> 1;                   // 0..127
    const int r = rt >> 4, t = rt & 15;
    const int half = tid & 1;                  // 64-col half
    short* wrow = &Wb[(d * 128 + r * 16 + t) * 1024 + a * 128 + half * 64];
    for (int blk = 0; blk < 8; ++blk) {
        s16x8 v;
#pragma unroll
        for (int m = 0; m < 8; ++m) {
            int bc = half * 64 + blk * 8 + m;
            int b = bc >> 4, c = bc & 15;
            const float* t2p = &T2s[(b * 8 + r) * 16];
            const float* u3p = &u3[c * 256 + t * 16];
            float acc = 0.f;
#pragma unroll
            for (int s = 0; s < 16; ++s) acc += t2p[s] * u3p[s];
            v[m] = f2bf(acc);
        }
        *(s16x8*)(&wrow[blk * 8]) = v;
    }
}

// ---------------------------------------------------------------------------
// MFMA GEMM: H[z][o] = relu( sum_i X[z][i]*W[o][i] + bias[o] ), f32 out.
// 64x64 tile, BK=64, 4 waves (2x2), each wave 32x32 via 2x2 16x16x32 frags.
// X converted f32->bf16 during staging; reg-prefetch double buffer.
// LDS rows padded to 72 shorts (144B stride -> only 2-way bank alias, free).
// ---------------------------------------------------------------------------
#define LDK 72

__global__ __launch_bounds__(256) void k_gemm(
    const float* __restrict__ X, const short* __restrict__ Wb,
    const float* __restrict__ bias, float* __restrict__ H) {
    __shared__ short As[64][LDK];
    __shared__ short Bs[64][LDK];
    const int tid = threadIdx.x;
    const int lane = tid & 63;
    const int w = tid >> 6;
    const int wr = w >> 1, wc = w & 1;
    const int z0 = blockIdx.y * 64, o0 = blockIdx.x * 64;

    const int srow = tid >> 2;                 // 0..63
    const int skc = (tid & 3) * 16;            // 0,16,32,48

    const float* xp = &X[(z0 + srow) * 1024 + skc];
    const short* wp = &Wb[(o0 + srow) * 1024 + skc];

    f32x4 acc[2][2] = {};
    float4 ax[4];
    s16x8 bx[2];

#pragma unroll
    for (int q = 0; q < 4; ++q) ax[q] = *(const float4*)(xp + q * 4);
#pragma unroll
    for (int q = 0; q < 2; ++q) bx[q] = *(const s16x8*)(wp + q * 8);

    for (int k0 = 0; k0 < 1024; k0 += 64) {
        // regs -> LDS (convert X to bf16)
#pragma unroll
        for (int q = 0; q < 2; ++q) {
            s16x8 v;
            v[0] = f2bf(ax[2 * q].x); v[1] = f2bf(ax[2 * q].y);
            v[2] = f2bf(ax[2 * q].z); v[3] = f2bf(ax[2 * q].w);
            v[4] = f2bf(ax[2 * q + 1].x); v[5] = f2bf(ax[2 * q + 1].y);
            v[6] = f2bf(ax[2 * q + 1].z); v[7] = f2bf(ax[2 * q + 1].w);
            *(s16x8*)(&As[srow][skc + q * 8]) = v;
            *(s16x8*)(&Bs[srow][skc + q * 8]) = bx[q];
        }
        __syncthreads();
        // prefetch next K-tile while computing this one
        if (k0 + 64 < 1024) {
            const float* xi = xp + k0 + 64;
            const short* wi = wp + k0 + 64;
#pragma unroll
            for (int q = 0; q < 4; ++q) ax[q] = *(const float4*)(xi + q * 4);
#pragma unroll
            for (int q = 0; q < 2; ++q) bx[q] = *(const s16x8*)(wi + q * 8);
        }
#pragma unroll
        for (int ks = 0; ks < 2; ++ks) {
            const int kb = ks * 32 + (lane >> 4) * 8;
            s16x8 a0 = *(const s16x8*)(&As[wr * 32 + (lane & 15)][kb]);
            s16x8 a1 = *(const s16x8*)(&As[wr * 32 + 16 + (lane & 15)][kb]);
            s16x8 b0 = *(const s16x8*)(&Bs[wc * 32 + (lane & 15)][kb]);
            s16x8 b1 = *(const s16x8*)(&Bs[wc * 32 + 16 + (lane & 15)][kb]);
            acc[0][0] = __builtin_amdgcn_mfma_f32_16x16x32_bf16(a0, b0, acc[0][0], 0, 0, 0);
            acc[0][1] = __builtin_amdgcn_mfma_f32_16x16x32_bf16(a0, b1, acc[0][1], 0, 0, 0);
            acc[1][0] = __builtin_amdgcn_mfma_f32_16x16x32_bf16(a1, b0, acc[1][0], 0, 0, 0);
            acc[1][1] = __builtin_amdgcn_mfma_f32_16x16x32_bf16(a1, b1, acc[1][1], 0, 0, 0);
        }
        __syncthreads();
    }

    // C/D layout: col = lane&15, row = (lane>>4)*4 + j
#pragma unroll
    for (int m = 0; m < 2; ++m) {
#pragma unroll
        for (int n = 0; n < 2; ++n) {
            const int row = z0 + wr * 32 + m * 16 + (lane >> 4) * 4;
            const int col = o0 + wc * 32 + n * 16 + (lane & 15);
            const float bv = bias[col];
#pragma unroll
            for (int j = 0; j < 4; ++j)
                H[(row + j) * 1024 + col] = fmaxf(acc[m][n][j] + bv, 0.f);
        }
    }
}

// ---------------------------------------------------------------------------
// fc2: out[z][j] = sum_o H[z][o]*W2[j][o] + b[j].  One wave per z row.
// ---------------------------------------------------------------------------
__global__ __launch_bounds__(256) void k_fc2(const float* __restrict__ H,
                                             const float* __restrict__ W2,
                                             const float* __restrict__ B2v,
                                             float* __restrict__ out) {
    const int wave = threadIdx.x >> 6;
    const int lane = threadIdx.x & 63;
    const int z = blockIdx.x * 4 + wave;
    const float4* hp = (const float4*)(&H[z * 1024]);
    float4 h[4];
#pragma unroll
    for (int r = 0; r < 4; ++r) h[r] = hp[lane + 64 * r];
#pragma unroll
    for (int j = 0; j < 10; ++j) {
        const float4* wp = (const float4*)(&W2[j * 1024]);
        float s = 0.f;
#pragma unroll
        for (int r = 0; r < 4; ++r) {
            float4 wv = wp[lane + 64 * r];
            s += h[r].x * wv.x + h[r].y * wv.y + h[r].z * wv.z + h[r].w * wv.w;
        }
#pragma unroll
        for (int off = 32; off > 0; off >>= 1) s += __shfl_down(s, off);
        if (lane == 0) out[z * 10 + j] = s + B2v[j];
    }
}

extern "C" void kernel_launch(void* const* d_in, const int* in_sizes, int n_in,
                              void* d_out, int out_size, void* d_ws, size_t ws_size,
                              hipStream_t stream) {
    const float* x     = (const float*)d_in[0];
    const float* u1    = (const float*)d_in[1];
    const float* u2    = (const float*)d_in[2];
    const float* u3    = (const float*)d_in[3];
    const float* b2    = (const float*)d_in[4];
    const float* b1c   = (const float*)d_in[5];
    const float* bias1 = (const float*)d_in[6];
    const float* fc2w  = (const float*)d_in[7];
    const float* fc2b  = (const float*)d_in[8];
    float* out = (float*)d_out;

    short* Wb = (short*)d_ws;                                  // 2 MB
    float* H  = (float*)((char*)d_ws + 2u * 1024u * 1024u);    // 4 MB

    k_build_w<<<64, 256, 0, stream>>>(u1, u2, u3, b2, b1c, Wb);
    k_gemm<<<dim3(16, 16), 256, 0, stream>>>(x, Wb, bias1, H);
    k_fc2<<<256, 256, 0, stream>>>(H, fc2w, fc2b, out);
}

// Round 3
// 32.214 us; speedup vs baseline: 2.6105x; 1.2700x over previous
//
#include <hip/hip_runtime.h>

// ---------------------------------------------------------------------------
// tNet: einsum chain is linear in x. Kernel 1 builds W_eff (1024x1024 bf16)
// and inits out = fc2_b. Kernel 2 computes H = relu(X @ W^T + bias1) via bf16
// MFMA and fuses fc2 (out += H_tile @ fc2_w^T) with f32 atomics.
//   t5[z,d,r,t] = sum_{a,b,c,e,p,q,s} x[z,a,b,c] u1[a,d,e] b2[e,p,q]
//                                     u2[b,r,p] b1c[q,s] u3[c,t,s]
//   o = d*128+r*16+t ; i = a*128+b*16+c
// Staged: C2[e,p,s]=sum_q b2*b1c ; T1[ad,p,s]=sum_e u1*C2 ;
//         T2[ad,b,r,s]=sum_p T1*u2 ; W[o,i]=sum_s T2*u3
// ---------------------------------------------------------------------------

using s16x8 = __attribute__((ext_vector_type(8))) short;   // 8 bf16
using f32x4 = __attribute__((ext_vector_type(4))) float;

__device__ inline short f2bf(float f) {
    unsigned u = __builtin_bit_cast(unsigned, f);
    u += 0x7fffu + ((u >> 16) & 1u);          // round-to-nearest-even
    return (short)(u >> 16);
}

// grid 296: blocks 0..255 build W (block = ad*4 + row-quarter);
//           blocks 256..295 init out[1024][10] = fc2_b broadcast.
__global__ __launch_bounds__(256) void k_build_w(
    const float* __restrict__ u1, const float* __restrict__ u2,
    const float* __restrict__ u3, const float* __restrict__ b2,
    const float* __restrict__ b1c, const float* __restrict__ fc2b,
    short* __restrict__ Wb, float* __restrict__ out) {
    const int blk = blockIdx.x;
    const int tid = threadIdx.x;
    if (blk >= 256) {                          // out init: 40*256 = 10240
        int idx = (blk - 256) * 256 + tid;
        out[idx] = fc2b[idx % 10];
        return;
    }
    __shared__ float b1s[256];
    __shared__ float C2f[4096];
    __shared__ float T1s[256];
    __shared__ float T2s[1024];
    const int ad = blk >> 2, quarter = blk & 3;
    b1s[tid] = b1c[tid];
    __syncthreads();
    // C2[e,p,s]
    for (int j = 0; j < 16; ++j) {
        int idx = tid + 256 * j;
        int e = idx >> 8, p = (idx >> 4) & 15, s = idx & 15;
        float acc = 0.f;
#pragma unroll
        for (int q = 0; q < 16; ++q)
            acc += b2[e * 256 + p * 16 + q] * b1s[q * 16 + s];
        C2f[idx] = acc;
    }
    __syncthreads();
    // T1[p,s] for this ad
    {
        float acc = 0.f;
#pragma unroll
        for (int e = 0; e < 16; ++e)
            acc += u1[ad * 16 + e] * C2f[e * 256 + tid];
        T1s[tid] = acc;
    }
    __syncthreads();
    // T2[b,r,s]
    for (int j = 0; j < 4; ++j) {
        int idx = tid + 256 * j;
        int s = idx & 15, r = (idx >> 4) & 7, b = idx >> 7;
        float acc = 0.f;
#pragma unroll
        for (int p = 0; p < 16; ++p)
            acc += T1s[p * 16 + s] * u2[(b * 8 + r) * 16 + p];
        T2s[idx] = acc;
    }
    __syncthreads();
    // W rows: this block covers rt = quarter*32 + (tid>>3), cols b = tid&7.
    const int a = ad >> 3, d = ad & 7;
    const int rt = quarter * 32 + (tid >> 3);  // 0..127
    const int r = rt >> 4, t = rt & 15;
    const int b = tid & 7;
    const float* t2p = &T2s[(b * 8 + r) * 16];
    short* wrow = &Wb[(d * 128 + rt) * 1024 + a * 128 + b * 16];
    s16x8 v0, v1;
#pragma unroll
    for (int c = 0; c < 16; ++c) {
        const float* u3p = &u3[c * 256 + t * 16];
        float acc = 0.f;
#pragma unroll
        for (int s = 0; s < 16; ++s) acc += t2p[s] * u3p[s];
        short bf = f2bf(acc);
        if (c < 8) v0[c] = bf; else v1[c - 8] = bf;
    }
    *(s16x8*)(wrow) = v0;
    *(s16x8*)(wrow + 8) = v1;
}

// ---------------------------------------------------------------------------
// MFMA GEMM + fused fc2. 64x64 tile, BK=128, 4 waves (2x2), each wave 32x32
// via 2x2 16x16x32 bf16 frags. X converted f32->bf16 during staging;
// register-prefetch double buffer. LDS row stride 136 shorts (272B) ->
// wave ds_read_b128 is exactly bank-balanced.
// Epilogue: relu tile -> LDS (alias As), partial fc2 -> atomicAdd(out).
// ---------------------------------------------------------------------------
#define LDK 136

__global__ __launch_bounds__(256) void k_gemm(
    const float* __restrict__ X, const short* __restrict__ Wb,
    const float* __restrict__ bias, const float* __restrict__ W2,
    float* __restrict__ out) {
    __shared__ short As[64][LDK];
    __shared__ short Bs[64][LDK];
    __shared__ float W2s[10][64];
    const int tid = threadIdx.x;
    const int lane = tid & 63;
    const int w = tid >> 6, wr = w >> 1, wc = w & 1;
    const int z0 = blockIdx.y * 64, o0 = blockIdx.x * 64;
    const int srow = tid >> 2;                 // 0..63
    const int sc = (tid & 3) * 16;             // col base; halves at +0,+64

    if (tid < 160) {                           // stage fc2_w tile [10][64]
        int jj = (tid * 4) >> 6, c = (tid * 4) & 63;
        *(float4*)&W2s[jj][c] = *(const float4*)&W2[jj * 1024 + o0 + c];
    }

    const float* xp = &X[(z0 + srow) * 1024 + sc];
    const short* wp = &Wb[(o0 + srow) * 1024 + sc];

    f32x4 acc[2][2] = {};
    float4 ax[8];
    s16x8 bx[4];

#pragma unroll
    for (int h = 0; h < 2; ++h) {
#pragma unroll
        for (int q = 0; q < 4; ++q) ax[h * 4 + q] = *(const float4*)(xp + h * 64 + q * 4);
#pragma unroll
        for (int q = 0; q < 2; ++q) bx[h * 2 + q] = *(const s16x8*)(wp + h * 64 + q * 8);
    }

    for (int k0 = 0; k0 < 1024; k0 += 128) {
        // regs -> LDS (convert X to bf16)
#pragma unroll
        for (int h = 0; h < 2; ++h) {
#pragma unroll
            for (int q = 0; q < 2; ++q) {
                float4 lo = ax[h * 4 + 2 * q], hi = ax[h * 4 + 2 * q + 1];
                s16x8 v;
                v[0] = f2bf(lo.x); v[1] = f2bf(lo.y);
                v[2] = f2bf(lo.z); v[3] = f2bf(lo.w);
                v[4] = f2bf(hi.x); v[5] = f2bf(hi.y);
                v[6] = f2bf(hi.z); v[7] = f2bf(hi.w);
                *(s16x8*)&As[srow][sc + h * 64 + q * 8] = v;
                *(s16x8*)&Bs[srow][sc + h * 64 + q * 8] = bx[h * 2 + q];
            }
        }
        __syncthreads();
        if (k0 + 128 < 1024) {                 // prefetch next K-tile
            const float* xi = xp + k0 + 128;
            const short* wi = wp + k0 + 128;
#pragma unroll
            for (int h = 0; h < 2; ++h) {
#pragma unroll
                for (int q = 0; q < 4; ++q) ax[h * 4 + q] = *(const float4*)(xi + h * 64 + q * 4);
#pragma unroll
                for (int q = 0; q < 2; ++q) bx[h * 2 + q] = *(const s16x8*)(wi + h * 64 + q * 8);
            }
        }
#pragma unroll
        for (int ks = 0; ks < 4; ++ks) {
            const int kb = ks * 32 + (lane >> 4) * 8;
            s16x8 a0 = *(const s16x8*)&As[wr * 32 + (lane & 15)][kb];
            s16x8 a1 = *(const s16x8*)&As[wr * 32 + 16 + (lane & 15)][kb];
            s16x8 b0 = *(const s16x8*)&Bs[wc * 32 + (lane & 15)][kb];
            s16x8 b1 = *(const s16x8*)&Bs[wc * 32 + 16 + (lane & 15)][kb];
            acc[0][0] = __builtin_amdgcn_mfma_f32_16x16x32_bf16(a0, b0, acc[0][0], 0, 0, 0);
            acc[0][1] = __builtin_amdgcn_mfma_f32_16x16x32_bf16(a0, b1, acc[0][1], 0, 0, 0);
            acc[1][0] = __builtin_amdgcn_mfma_f32_16x16x32_bf16(a1, b0, acc[1][0], 0, 0, 0);
            acc[1][1] = __builtin_amdgcn_mfma_f32_16x16x32_bf16(a1, b1, acc[1][1], 0, 0, 0);
        }
        __syncthreads();
    }

    // ---- epilogue: relu H-tile into LDS (alias As: 64x136 shorts = 64x68 f32)
    float* Ht = (float*)As;
#pragma unroll
    for (int m = 0; m < 2; ++m) {
#pragma unroll
        for (int n = 0; n < 2; ++n) {
            const int row = wr * 32 + m * 16 + (lane >> 4) * 4;
            const int col = wc * 32 + n * 16 + (lane & 15);
            const float bv = bias[o0 + col];
#pragma unroll
            for (int j = 0; j < 4; ++j)
                Ht[(row + j) * 68 + col] = fmaxf(acc[m][n][j] + bv, 0.f);
        }
    }
    __syncthreads();

    // ---- fused fc2: 4 threads per z-row, stride-4 interleaved cols
    const int rrow = tid >> 2, q = tid & 3;
    float part[10];
#pragma unroll
    for (int jj = 0; jj < 10; ++jj) part[jj] = 0.f;
#pragma unroll
    for (int cc = 0; cc < 16; ++cc) {
        const int c = q + 4 * cc;
        const float hv = Ht[rrow * 68 + c];
#pragma unroll
        for (int jj = 0; jj < 10; ++jj) part[jj] += hv * W2s[jj][c];
    }
#pragma unroll
    for (int jj = 0; jj < 10; ++jj) {
        float p = part[jj];
        p += __shfl_xor(p, 1);
        p += __shfl_xor(p, 2);
        if (q == 0) atomicAdd(&out[(z0 + rrow) * 10 + jj], p);
    }
}

extern "C" void kernel_launch(void* const* d_in, const int* in_sizes, int n_in,
                              void* d_out, int out_size, void* d_ws, size_t ws_size,
                              hipStream_t stream) {
    const float* x     = (const float*)d_in[0];
    const float* u1    = (const float*)d_in[1];
    const float* u2    = (const float*)d_in[2];
    const float* u3    = (const float*)d_in[3];
    const float* b2    = (const float*)d_in[4];
    const float* b1c   = (const float*)d_in[5];
    const float* bias1 = (const float*)d_in[6];
    const float* fc2w  = (const float*)d_in[7];
    const float* fc2b  = (const float*)d_in[8];
    float* out = (float*)d_out;

    short* Wb = (short*)d_ws;                  // 2 MB bf16 W_eff

    k_build_w<<<296, 256, 0, stream>>>(u1, u2, u3, b2, b1c, fc2b, Wb, out);
    k_gemm<<<dim3(16, 16), 256, 0, stream>>>(x, Wb, bias1, fc2w, out);
}